// Round 5
// baseline (505.071 us; speedup 1.0000x reference)
//
#include <hip/hip_runtime.h>
#include <cstddef>

#define B_   4
#define S_   8192
#define D_   512
#define H_   8
#define HD_  64
#define NROW (B_ * S_)              // 32768
#define NQ   ((size_t)NROW * D_)    // 16777216 elements per q/k/v buffer

typedef __attribute__((ext_vector_type(4))) float  f32x4;
typedef __attribute__((ext_vector_type(8))) short  s16x8;
typedef __attribute__((ext_vector_type(4))) unsigned short u16x4;
typedef __attribute__((ext_vector_type(8))) unsigned short u16x8;

__device__ __forceinline__ float phi_f(float x) {
    return x > 0.0f ? x + 1.0f : expf(x);   // elu(x)+1
}
__device__ __forceinline__ float bf2f(unsigned short u) {
    return __uint_as_float(((unsigned int)u) << 16);
}
__device__ __forceinline__ unsigned short f2bf(float f) {
    unsigned int u = __float_as_uint(f);
    u += 0x7fffu + ((u >> 16) & 1u);        // round-to-nearest-even
    return (unsigned short)(u >> 16);
}

#define GLOBAL_AS(p) ((const __attribute__((address_space(1))) void*)(p))
#define LDS_AS(p)    ((__attribute__((address_space(3))) void*)(p))

// ---------------------------------------------------------------------------
// Mask layout detector: 1 = byte-per-element (bool), 0 = 4-byte layout.
// ---------------------------------------------------------------------------
__global__ void detect_mask(const unsigned char* __restrict__ m, int* __restrict__ flag) {
    __shared__ int sany;
    if (threadIdx.x == 0) sany = 0;
    __syncthreads();
    int any = 0;
    for (int i = 1 + 4 * (int)threadIdx.x; i < NROW; i += 4 * 256) any |= m[i];
    if (any) atomicOr(&sany, 1);
    __syncthreads();
    if (threadIdx.x == 0) *flag = sany ? 1 : 0;
}

// ---------------------------------------------------------------------------
// Convert query/w_in/w_out -> bf16; mask -> float (1.0 keep / 0.0 ignore).
// ---------------------------------------------------------------------------
__global__ __launch_bounds__(256) void convert_all(
    const float* __restrict__ q,  unsigned short* __restrict__ qb,
    const float* __restrict__ wi, unsigned short* __restrict__ wib,
    const float* __restrict__ wo, unsigned short* __restrict__ wob,
    const unsigned char* __restrict__ kpm, const int* __restrict__ flag,
    float* __restrict__ fmask)
{
    const size_t i = (size_t)blockIdx.x * 256 + threadIdx.x;
    {   // query: 16777216 / 4 = 4194304 threads exactly
        const float4 v = *(const float4*)&q[i * 4];
        u16x4 o; o.x = f2bf(v.x); o.y = f2bf(v.y); o.z = f2bf(v.z); o.w = f2bf(v.w);
        *(u16x4*)&qb[i * 4] = o;
    }
    if (i < 786432 / 4) {
        const float4 v = *(const float4*)&wi[i * 4];
        u16x4 o; o.x = f2bf(v.x); o.y = f2bf(v.y); o.z = f2bf(v.z); o.w = f2bf(v.w);
        *(u16x4*)&wib[i * 4] = o;
    }
    if (i < 262144 / 4) {
        const float4 v = *(const float4*)&wo[i * 4];
        u16x4 o; o.x = f2bf(v.x); o.y = f2bf(v.y); o.z = f2bf(v.z); o.w = f2bf(v.w);
        *(u16x4*)&wob[i * 4] = o;
    }
    if (i < NROW) {
        const bool ignore = (*flag) ? (kpm[i] != 0) : (((const int*)kpm)[i] != 0);
        fmask[i] = ignore ? 0.0f : 1.0f;
    }
}

// ---------------------------------------------------------------------------
// bf16 MFMA GEMM: C[m][n] = sum_k A[m][k]*B[n][k] + bias[n].
// R5 retile: BM=256, BN=128, BK=32, 256 thr = 4 waves, each wave owns
// 64m x 128n via 4x8 frags of 16x16x32_bf16. Rationale: K=512 gives only
// 16 K-iters; at BM=128 the wave did 16 MFMA (~78cyc) vs 8 ds_read_b128
// (~96cyc) per iter -> LDS-issue-bound (MfmaUtil 19%). BM=256 doubles
// MFMA per LDS byte: 32 MFMA vs 12 ds_read.
// global_load_lds width=16, unpadded k-contig LDS (wave-uniform-base rule).
// mode 0: in-proj epilogue -> phi / phi*mask / *mask into q/k/v bf16 buffers.
// mode 1: out-proj epilogue -> fp32 to Cout.
// ---------------------------------------------------------------------------
__global__ __launch_bounds__(256) void gemm_mfma(
    const unsigned short* __restrict__ A,  int lda,
    const unsigned short* __restrict__ Bw, int ldb,
    const float* __restrict__ bias, int K, int mode,
    const float* __restrict__ fmask,
    unsigned short* __restrict__ Cq,
    unsigned short* __restrict__ Ck,
    unsigned short* __restrict__ Cv,
    float* __restrict__ Cout)
{
    __shared__ __align__(16) unsigned short As[256 * 32];  // [m][k], 64B rows, 16 KB
    __shared__ __align__(16) unsigned short Bs[128 * 32];  // [n][k], 8 KB
    __shared__ float fm[256];

    const int t    = threadIdx.x;
    const int lane = t & 63;
    const int wave = t >> 6;            // 0..3; wave owns m-rows [wave*64, +64)
    const int m0   = blockIdx.y * 256;
    const int n0   = blockIdx.x * 128;

    if (mode == 0) fm[t] = fmask[m0 + t];

    f32x4 acc[4][8] = {};

    const int sr = lane >> 2;           // staging row-in-16 group
    const int sk = (lane & 3) * 8;      // staging k element offset (16B chunks)

    for (int k0 = 0; k0 < K; k0 += 32) {
        __syncthreads();                // LDS free to overwrite
        #pragma unroll
        for (int j = 0; j < 4; ++j) {   // A: wave stages rows [wave*64, +64)
            const int row = wave * 64 + j * 16;
            const unsigned short* g = A + (size_t)(m0 + row + sr) * lda + k0 + sk;
            __builtin_amdgcn_global_load_lds(GLOBAL_AS(g), LDS_AS(&As[row * 32]), 16, 0, 0);
        }
        #pragma unroll
        for (int j = 0; j < 2; ++j) {   // B: wave stages rows [wave*32, +32)
            const int row = wave * 32 + j * 16;
            const unsigned short* g = Bw + (size_t)(n0 + row + sr) * ldb + k0 + sk;
            __builtin_amdgcn_global_load_lds(GLOBAL_AS(g), LDS_AS(&Bs[row * 32]), 16, 0, 0);
        }
        __syncthreads();                // staging complete (vmcnt drained at barrier)

        const int fr = lane & 15;       // m (or n) within 16
        const int fk = (lane >> 4) * 8; // k offset within 32
        s16x8 af[4], bf[8];
        #pragma unroll
        for (int i = 0; i < 4; ++i)
            af[i] = *(const s16x8*)&As[(wave * 64 + i * 16 + fr) * 32 + fk];
        #pragma unroll
        for (int j = 0; j < 8; ++j)
            bf[j] = *(const s16x8*)&Bs[(j * 16 + fr) * 32 + fk];
        #pragma unroll
        for (int i = 0; i < 4; ++i)
            #pragma unroll
            for (int j = 0; j < 8; ++j)
                acc[i][j] = __builtin_amdgcn_mfma_f32_16x16x32_bf16(af[i], bf[j], acc[i][j], 0, 0, 0);
    }

    // Epilogue. C/D layout: n = lane&15, m = (lane>>4)*4 + reg.
    const int col  = lane & 15;
    const int rowq = (lane >> 4) * 4;
    float bj[8];
    #pragma unroll
    for (int j = 0; j < 8; ++j) bj[j] = bias[n0 + j * 16 + col];

    if (mode == 1) {
        #pragma unroll
        for (int i = 0; i < 4; ++i)
            #pragma unroll
            for (int r = 0; r < 4; ++r) {
                const int m = m0 + wave * 64 + i * 16 + rowq + r;
                #pragma unroll
                for (int j = 0; j < 8; ++j) {
                    const int n = n0 + j * 16 + col;
                    Cout[(size_t)m * D_ + n] = acc[i][j][r] + bj[j];
                }
            }
    } else {
        const int region = n0 >> 9;     // 0:q 1:k 2:v (BN=128 divides 512)
        unsigned short* Cb = region == 0 ? Cq : (region == 1 ? Ck : Cv);
        #pragma unroll
        for (int i = 0; i < 4; ++i)
            #pragma unroll
            for (int r = 0; r < 4; ++r) {
                const int ml = wave * 64 + i * 16 + rowq + r;
                const int m  = m0 + ml;
                const float mk = fm[ml];
                #pragma unroll
                for (int j = 0; j < 8; ++j) {
                    const int n  = (n0 & 511) + j * 16 + col;
                    float v = acc[i][j][r] + bj[j];
                    if (region == 0)      v = phi_f(v);
                    else if (region == 1) v = phi_f(v) * mk;
                    else                  v = v * mk;
                    Cb[(size_t)m * D_ + n] = f2bf(v);
                }
            }
    }
}

// ---------------------------------------------------------------------------
// Per (head, S-chunk) partial kv = k^T v (64x64) and k_sum. bf16 in, fp32 out.
// ---------------------------------------------------------------------------
__global__ __launch_bounds__(256) void kv_reduce(
    const unsigned short* __restrict__ kbuf,   // [NROW][512] bf16
    const unsigned short* __restrict__ vbuf,
    float* __restrict__ part_kv,               // [512][4096]
    float* __restrict__ part_ks)               // [512][64]
{
    const int bh = blockIdx.x, chunk = blockIdx.y;
    const int b = bh >> 3, h = bh & 7;

    __shared__ __align__(16) float Ks[16][64];
    __shared__ __align__(16) float Vs[16][64];

    const int t  = threadIdx.x;
    const int tx = t & 15, ty = t >> 4;
    const int ls = t >> 4;
    const int lc = (t & 15) * 4;

    const unsigned short* kb = kbuf + (size_t)b * S_ * D_ + h * HD_;
    const unsigned short* vb = vbuf + (size_t)b * S_ * D_ + h * HD_;

    float acc[4][4] = {};
    float ks[4] = {};
    const int s0 = chunk * (S_ / 16);

    for (int it = 0; it < S_ / 16; it += 16) {
        const size_t s = (size_t)(s0 + it + ls);
        const u16x4 kk = *(const u16x4*)&kb[s * D_ + lc];
        const u16x4 vv = *(const u16x4*)&vb[s * D_ + lc];
        Ks[ls][lc + 0] = bf2f(kk.x); Ks[ls][lc + 1] = bf2f(kk.y);
        Ks[ls][lc + 2] = bf2f(kk.z); Ks[ls][lc + 3] = bf2f(kk.w);
        Vs[ls][lc + 0] = bf2f(vv.x); Vs[ls][lc + 1] = bf2f(vv.y);
        Vs[ls][lc + 2] = bf2f(vv.z); Vs[ls][lc + 3] = bf2f(vv.w);
        __syncthreads();
        #pragma unroll
        for (int ss = 0; ss < 16; ++ss) {
            const float4 a = *(const float4*)&Ks[ss][ty * 4];
            const float4 v = *(const float4*)&Vs[ss][tx * 4];
            acc[0][0] += a.x * v.x; acc[0][1] += a.x * v.y; acc[0][2] += a.x * v.z; acc[0][3] += a.x * v.w;
            acc[1][0] += a.y * v.x; acc[1][1] += a.y * v.y; acc[1][2] += a.y * v.z; acc[1][3] += a.y * v.w;
            acc[2][0] += a.z * v.x; acc[2][1] += a.z * v.y; acc[2][2] += a.z * v.z; acc[2][3] += a.z * v.w;
            acc[3][0] += a.w * v.x; acc[3][1] += a.w * v.y; acc[3][2] += a.w * v.z; acc[3][3] += a.w * v.w;
            if (tx == 0) { ks[0] += a.x; ks[1] += a.y; ks[2] += a.z; ks[3] += a.w; }
        }
        __syncthreads();
    }

    float* pk = part_kv + (size_t)(bh * 16 + chunk) * 4096;
    #pragma unroll
    for (int i = 0; i < 4; ++i) {
        float4 o; o.x = acc[i][0]; o.y = acc[i][1]; o.z = acc[i][2]; o.w = acc[i][3];
        *(float4*)&pk[(ty * 4 + i) * HD_ + tx * 4] = o;
    }
    if (tx == 0) {
        float* ps = part_ks + (size_t)(bh * 16 + chunk) * HD_;
        #pragma unroll
        for (int i = 0; i < 4; ++i) ps[ty * 4 + i] = ks[i];
    }
}

__global__ void kv_reduce2(const float* __restrict__ part_kv,
                           const float* __restrict__ part_ks,
                           float* __restrict__ kv, float* __restrict__ ksum)
{
    const int i = blockIdx.x * 256 + threadIdx.x;
    if (i < 32 * 4096) {
        const int bh = i >> 12, e = i & 4095;
        float s = 0.0f;
        #pragma unroll
        for (int c = 0; c < 16; ++c) s += part_kv[(size_t)(bh * 16 + c) * 4096 + e];
        kv[i] = s;
    }
    if (i < 32 * 64) {
        const int bh = i >> 6, e = i & 63;
        float s = 0.0f;
        #pragma unroll
        for (int c = 0; c < 16; ++c) s += part_ks[(size_t)(bh * 16 + c) * 64 + e];
        ksum[i] = s;
    }
}

// ---------------------------------------------------------------------------
// attn[s][e] = (q[s]·kv[:,e]) / max(q[s]·ksum, 1e-6).  q bf16 in, attn bf16 out.
// ---------------------------------------------------------------------------
__global__ __launch_bounds__(256) void apply_attn(
    const unsigned short* __restrict__ qbuf,   // [NROW][512] bf16 (phi'd)
    const float* __restrict__ kv,
    const float* __restrict__ ksum,
    unsigned short* __restrict__ attnb)        // [NROW][512] bf16
{
    const int bh = blockIdx.x;
    const int sb = blockIdx.y * 64;
    const int b = bh >> 3, h = bh & 7;

    __shared__ __align__(16) float Qs[64][68];    // [d][s] transposed
    __shared__ __align__(16) float KVs[64][68];   // [d][e]
    __shared__ float ksums[64];
    __shared__ float dens[64];

    const int t  = threadIdx.x;
    const int tx = t & 15, ty = t >> 4;

    {   // stage kv head + ksum
        const float* kvh = kv + (size_t)bh * 4096;
        #pragma unroll
        for (int i = 0; i < 4; ++i) {
            const int d = (t >> 4) + i * 16;
            const int e = (t & 15) * 4;
            *(float4*)&KVs[d][e] = *(const float4*)&kvh[d * HD_ + e];
        }
        if (t < 16) {
            const float4 kk = *(const float4*)&ksum[bh * HD_ + t * 4];
            ksums[t * 4 + 0] = kk.x; ksums[t * 4 + 1] = kk.y;
            ksums[t * 4 + 2] = kk.z; ksums[t * 4 + 3] = kk.w;
        }
    }
    {   // stage q tile transposed: each thread 16 contiguous bf16 of one row
        const int s_l = t >> 2;
        const int dq  = (t & 3) * 16;
        const unsigned short* qrow = qbuf + (size_t)(b * S_ + sb + s_l) * D_ + h * HD_;
        const u16x8 q0 = *(const u16x8*)&qrow[dq];
        const u16x8 q1 = *(const u16x8*)&qrow[dq + 8];
        #pragma unroll
        for (int e = 0; e < 8; ++e) Qs[dq + e][s_l] = bf2f(q0[e]);
        #pragma unroll
        for (int e = 0; e < 8; ++e) Qs[dq + 8 + e][s_l] = bf2f(q1[e]);
    }
    __syncthreads();

    float acc[4][4] = {};
    float den[4] = {};
    // Partial unroll: full 64x unroll spilled past 256 VGPRs (R3: 2 GB scratch).
    #pragma unroll 4
    for (int d = 0; d < 64; ++d) {
        const float4 a  = *(const float4*)&Qs[d][ty * 4];
        const float4 bv = *(const float4*)&KVs[d][tx * 4];
        acc[0][0] += a.x * bv.x; acc[0][1] += a.x * bv.y; acc[0][2] += a.x * bv.z; acc[0][3] += a.x * bv.w;
        acc[1][0] += a.y * bv.x; acc[1][1] += a.y * bv.y; acc[1][2] += a.y * bv.z; acc[1][3] += a.y * bv.w;
        acc[2][0] += a.z * bv.x; acc[2][1] += a.z * bv.y; acc[2][2] += a.z * bv.z; acc[2][3] += a.z * bv.w;
        acc[3][0] += a.w * bv.x; acc[3][1] += a.w * bv.y; acc[3][2] += a.w * bv.z; acc[3][3] += a.w * bv.w;
        if (tx == 0) {
            const float kd = ksums[d];
            den[0] += a.x * kd; den[1] += a.y * kd; den[2] += a.z * kd; den[3] += a.w * kd;
        }
    }
    if (tx == 0) {
        #pragma unroll
        for (int i = 0; i < 4; ++i) dens[ty * 4 + i] = den[i];
    }
    __syncthreads();

    #pragma unroll
    for (int i = 0; i < 4; ++i) {
        const float inv = 1.0f / fmaxf(dens[ty * 4 + i], 1e-6f);
        u16x4 o;
        o.x = f2bf(acc[i][0] * inv); o.y = f2bf(acc[i][1] * inv);
        o.z = f2bf(acc[i][2] * inv); o.w = f2bf(acc[i][3] * inv);
        const size_t r = (size_t)(b * S_ + sb + ty * 4 + i);
        *(u16x4*)&attnb[r * D_ + h * HD_ + tx * 4] = o;
    }
}

// ---------------------------------------------------------------------------
extern "C" void kernel_launch(void* const* d_in, const int* in_sizes, int n_in,
                              void* d_out, int out_size, void* d_ws, size_t ws_size,
                              hipStream_t stream)
{
    const float* query       = (const float*)d_in[0];
    const unsigned char* kpm = (const unsigned char*)d_in[3];
    const float* w_in        = (const float*)d_in[4];
    const float* b_in        = (const float*)d_in[5];
    const float* w_out       = (const float*)d_in[6];
    const float* b_out       = (const float*)d_in[7];
    float* out = (float*)d_out;

    // workspace layout
    unsigned short* qb    = (unsigned short*)d_ws;          // query bf16     33.5 MB
    unsigned short* qphi  = qb    + NQ;                     // phi(q)         33.5 MB
    unsigned short* kpb   = qphi  + NQ;                     // phi(k)*mask    33.5 MB
    unsigned short* vmb   = kpb   + NQ;                     // v*mask         33.5 MB
    unsigned short* attnb = vmb   + NQ;                     // attn           33.5 MB
    unsigned short* wib   = attnb + NQ;                     // w_in bf16       1.6 MB
    unsigned short* wob   = wib   + 1536 * 512;             // w_out bf16      0.5 MB
    float* fmask   = (float*)(wob + 512 * 512);             // 128 KB
    float* part_kv = fmask + NROW;                          // 8.4 MB
    float* part_ks = part_kv + (size_t)512 * 4096;
    float* kv      = part_ks + 512 * 64;
    float* ksum    = kv + 32 * 4096;
    int*   flag    = (int*)(ksum + 32 * 64);

    hipLaunchKernelGGL(detect_mask, dim3(1), dim3(256), 0, stream, kpm, flag);
    hipLaunchKernelGGL(convert_all, dim3(16384), dim3(256), 0, stream,
                       query, qb, w_in, wib, w_out, wob, kpm, flag, fmask);

    // in-proj: M=32768, N=1536, K=512; epilogue -> qphi/kpb/vmb (bf16)
    hipLaunchKernelGGL(gemm_mfma, dim3(1536 / 128, NROW / 256), dim3(256), 0, stream,
                       qb, D_, wib, D_, b_in, D_, 0, fmask,
                       qphi, kpb, vmb, (float*)nullptr);

    hipLaunchKernelGGL(kv_reduce, dim3(32, 16), dim3(256), 0, stream, kpb, vmb, part_kv, part_ks);
    hipLaunchKernelGGL(kv_reduce2, dim3((32 * 4096) / 256), dim3(256), 0, stream,
                       part_kv, part_ks, kv, ksum);
    hipLaunchKernelGGL(apply_attn, dim3(32, S_ / 64), dim3(256), 0, stream, qphi, kv, ksum, attnb);

    // out-proj: M=32768, N=512, K=512 -> fp32 d_out
    hipLaunchKernelGGL(gemm_mfma, dim3(512 / 128, NROW / 256), dim3(256), 0, stream,
                       attnb, D_, wob, D_, b_out, D_, 1, (const float*)nullptr,
                       (unsigned short*)nullptr, (unsigned short*)nullptr,
                       (unsigned short*)nullptr, out);
}